// Round 15
// baseline (40.906 us; speedup 1.0000x reference)
//
#include <hip/hip_runtime.h>

typedef float f32x4 __attribute__((ext_vector_type(4)));
typedef int   i32x4 __attribute__((ext_vector_type(4)));
typedef unsigned int u32;

#define HW_N  4096
#define C_N   128
#define G_N   16
#define K_N   2048
#define O_N   256
#define BN    256

__device__ __forceinline__ u32 pack4(float a, float b, float c, float d, float inv) {
  int q0 = (int)rintf(a * inv), q1 = (int)rintf(b * inv);
  int q2 = (int)rintf(c * inv), q3 = (int)rintf(d * inv);
  return (u32)(q0 & 255) | ((u32)(q1 & 255) << 8) |
         ((u32)(q2 & 255) << 16) | ((u32)(q3 & 255) << 24);
}

// ---- prep: W2 f32 [256][2048] -> i8 fragment-tiled + per-row scale sw ----
// frag id = mtile*32 + g*2 + ks2 (16x64 i8 tile); lane l holds
// row = mtile*16 + (l&15), k = g*128 + ks2*64 + (l>>4)*16 + j, 16 B per lane.
// One wave per W2 row, one block per CU (256 blocks x 64 threads).
__global__ void w2q_k(const float* __restrict__ W2, char* __restrict__ w2q,
                      float* __restrict__ sw) {
  int o = blockIdx.x;                  // 0..255
  int l = threadIdx.x;                 // 0..63
  const f32x4* rp = reinterpret_cast<const f32x4*>(W2 + (size_t)o * K_N + l * 32);
  float v[32]; float am = 0.f;
#pragma unroll
  for (int q = 0; q < 8; ++q) {
    f32x4 t = rp[q];
#pragma unroll
    for (int j = 0; j < 4; ++j) { v[q * 4 + j] = t[j]; am = fmaxf(am, fabsf(t[j])); }
  }
#pragma unroll
  for (int s = 1; s < 64; s <<= 1) am = fmaxf(am, __shfl_xor(am, s, 64));
  am = fmaxf(am, 1e-30f);
  float inv = 127.0f / am;
  if (l == 0) sw[o] = am / 127.0f;
#pragma unroll
  for (int c = 0; c < 2; ++c) {
    int k0 = l * 32 + c * 16;
    u32 pk[4];
#pragma unroll
    for (int q = 0; q < 4; ++q)
      pk[q] = pack4(v[c * 16 + q * 4 + 0], v[c * 16 + q * 4 + 1],
                    v[c * 16 + q * 4 + 2], v[c * 16 + q * 4 + 3], inv);
    int frag = (o >> 4) * 32 + (k0 >> 7) * 2 + ((k0 >> 6) & 1);
    int lif  = (o & 15) + ((k0 >> 4) & 3) * 16;
    *reinterpret_cast<i32x4*>(w2q + (size_t)frag * 1024 + lif * 16) =
        *reinterpret_cast<i32x4*>(pk);
  }
}

// ---- main fused kernel ----
// out[o,p] = b2[o] + sw[o]*sx[p] * sum_g fm[g,p] * P_g[o,p],
// P_g = i8-dot of qw (group g cols) and qx (exact i32 accumulate).
// Block: 128 o x 256 px, 8 waves (2 wm x 4 wn), wave tile 64o x 64px.
// BN=256 halves L2 A-traffic vs BN=128 (total 64 MB): per-CU load ~292
// cyc/group ~ matrix 326 cyc/group -> balanced. Zero barriers in main loop.
__launch_bounds__(512, 2)
__global__ void ccattn_main_k(const float* __restrict__ x,
                              const float* __restrict__ W1,
                              const float* __restrict__ b1,
                              const char* __restrict__ w2q,
                              const float* __restrict__ sw,
                              const float* __restrict__ b2,
                              float* __restrict__ out) {
  __shared__ char  qxT[BN * 128];      // 32 KB, [px][c] i8, granule-swizzled
  __shared__ float fmT[G_N][BN];       // 16 KB
  __shared__ float sxT[BN];            // 1 KB
  __shared__ float lmax[2][BN];        // 2 KB

  const int tid = threadIdx.x;
  const int bid = blockIdx.x;
  const int mt  = bid >> 7;            // pt-major: co-resident blocks share mt
  const int pt  = bid & 127;
  const int b   = pt >> 4;
  const int px0 = (pt & 15) * BN;

  const float* xb = x + (size_t)b * C_N * HW_N + px0;

  // ---- staging pass A: read x (exact f32), fm, per-half absmax ----
  const int px    = tid & 255;
  const int chalf = tid >> 8;          // channels [0,64) or [64,128)
  float v[8][8];
  {
    float am = 0.f;
#pragma unroll
    for (int gg = 0; gg < 8; ++gg) {
      const int g  = chalf * 8 + gg;
      const int c0 = g * 8;
      float s = b1[g];
#pragma unroll
      for (int j = 0; j < 8; ++j) {
        float t = xb[(size_t)(c0 + j) * HW_N + px];
        v[gg][j] = t;
        s += t * W1[g * 8 + j];
        am = fmaxf(am, fabsf(t));
      }
      fmT[g][px] = fmaxf(s, 0.0f);
    }
    lmax[chalf][px] = am;
  }
  __syncthreads();

  // ---- staging pass B: per-pixel scale + quantize to qxT ----
  {
    float amax = fmaxf(fmaxf(lmax[0][px], lmax[1][px]), 1e-30f);
    float inv  = 127.0f / amax;
    if (!chalf) sxT[px] = amax / 127.0f;
#pragma unroll
    for (int gr = 0; gr < 4; ++gr) {   // 4 granules of 16 channels each
      u32 pk[4];
#pragma unroll
      for (int q = 0; q < 4; ++q) {
        const int gg = gr * 2 + (q >> 1);
        const int j0 = (q & 1) * 4;
        pk[q] = pack4(v[gg][j0], v[gg][j0 + 1], v[gg][j0 + 2], v[gg][j0 + 3], inv);
      }
      int gidx = chalf * 4 + gr;
      int byte = px * 128 + ((gidx ^ (px & 7)) << 4);
      *reinterpret_cast<i32x4*>(qxT + byte) = *reinterpret_cast<i32x4*>(pk);
    }
  }
  __syncthreads();

  // ---- wave decomposition ----
  const int w  = tid >> 6;             // 0..7
  const int l  = tid & 63;
  const int wm = w & 1;                // o offset 0/64
  const int wn = w >> 1;               // px offset 0/64/128/192
  const int lc = l & 15;
  const int lk = l >> 4;

  // ---- B-fragment register cache [ks2][nf] (group-invariant!) ----
  i32x4 bfr[2][4];
#pragma unroll
  for (int ks2 = 0; ks2 < 2; ++ks2)
#pragma unroll
    for (int nf = 0; nf < 4; ++nf) {
      int p    = wn * 64 + nf * 16 + lc;
      int gidx = ks2 * 4 + lk;
      int byte = p * 128 + ((gidx ^ (p & 7)) << 4);
      bfr[ks2][nf] = *reinterpret_cast<const i32x4*>(qxT + byte);
    }

  f32x4 acc[4][4];
  const f32x4 Z = {0.f, 0.f, 0.f, 0.f};
#pragma unroll
  for (int mf = 0; mf < 4; ++mf)
#pragma unroll
    for (int nf = 0; nf < 4; ++nf) acc[mf][nf] = Z;

  // A base: frag byte = mtile*32768 + g*2048 + ks2*1024 + l*16
  const char* abm = w2q + (size_t)(mt * 8 + wm * 4) * 32768 + l * 16;

  i32x4 A0[8], A1[8];
  float snC[4], snN[4];

#define LDG(dst, g)                                                          \
  {                                                                          \
    _Pragma("unroll")                                                        \
    for (int mf = 0; mf < 4; ++mf) {                                         \
      dst[mf * 2]     = *reinterpret_cast<const i32x4*>(abm + (size_t)mf * 32768 + (g) * 2048);        \
      dst[mf * 2 + 1] = *reinterpret_cast<const i32x4*>(abm + (size_t)mf * 32768 + (g) * 2048 + 1024); \
    }                                                                        \
  }
#define LDSN(dst, g)                                                         \
  {                                                                          \
    _Pragma("unroll")                                                        \
    for (int nf = 0; nf < 4; ++nf) dst[nf] = fmT[g][wn * 64 + nf * 16 + lc]; \
  }
#define COMP(buf, sn)                                                        \
  {                                                                          \
    __builtin_amdgcn_s_setprio(1);                                           \
    _Pragma("unroll")                                                        \
    for (int nf = 0; nf < 4; ++nf) {                                         \
      i32x4 P[4];                                                            \
      _Pragma("unroll")                                                      \
      for (int mf = 0; mf < 4; ++mf)                                         \
        P[mf] = __builtin_amdgcn_mfma_i32_16x16x64_i8(                       \
            buf[mf * 2], bfr[0][nf], (i32x4){0, 0, 0, 0}, 0, 0, 0);          \
      _Pragma("unroll")                                                      \
      for (int mf = 0; mf < 4; ++mf)                                         \
        P[mf] = __builtin_amdgcn_mfma_i32_16x16x64_i8(                       \
            buf[mf * 2 + 1], bfr[1][nf], P[mf], 0, 0, 0);                    \
      _Pragma("unroll")                                                      \
      for (int mf = 0; mf < 4; ++mf) {                                       \
        _Pragma("unroll")                                                    \
        for (int i = 0; i < 4; ++i)                                          \
          acc[mf][nf][i] += sn[nf] * (float)P[mf][i];                        \
      }                                                                      \
    }                                                                        \
    __builtin_amdgcn_s_setprio(0);                                           \
  }

  LDG(A0, 0)
  LDSN(snC, 0)

  // ---- main loop: 16 groups, unroll-2, full-group reg-dbuf, no barriers ----
#pragma unroll 1
  for (int g = 0; g < 16; g += 2) {
    LDG(A1, g + 1)
    LDSN(snN, g + 1)
    COMP(A0, snC)
    const int g2 = (g + 2 < 16) ? g + 2 : 15;   // clamped dup load (harmless)
    LDG(A0, g2)
    LDSN(snC, g2)
    COMP(A1, snN)
  }
#undef LDG
#undef LDSN
#undef COMP

  // ---- epilogue: out = acc*sw[o]*sx[p] + b2[o] ----
  float sxv[4];
#pragma unroll
  for (int nf = 0; nf < 4; ++nf) sxv[nf] = sxT[wn * 64 + nf * 16 + lc];
  float* outb = out + (size_t)b * O_N * HW_N + px0;
#pragma unroll
  for (int mf = 0; mf < 4; ++mf) {
    int o0 = mt * 128 + wm * 64 + mf * 16 + lk * 4;
#pragma unroll
    for (int i = 0; i < 4; ++i) {
      float so   = sw[o0 + i];
      float bias = b2[o0 + i];
#pragma unroll
      for (int nf = 0; nf < 4; ++nf) {
        int p = wn * 64 + nf * 16 + lc;
        outb[(size_t)(o0 + i) * HW_N + p] = acc[mf][nf][i] * so * sxv[nf] + bias;
      }
    }
  }
}

extern "C" void kernel_launch(void* const* d_in, const int* in_sizes, int n_in,
                              void* d_out, int out_size, void* d_ws, size_t ws_size,
                              hipStream_t stream) {
  const float* x  = (const float*)d_in[0];
  const float* W1 = (const float*)d_in[1];
  const float* b1 = (const float*)d_in[2];
  const float* W2 = (const float*)d_in[3];
  const float* b2 = (const float*)d_in[4];
  float* out = (float*)d_out;
  char*  w2q = (char*)d_ws;                       // 512 KB i8 tiled W2
  float* sw  = (float*)((char*)d_ws + 524288);    // 256 f32 row scales

  w2q_k<<<256, 64, 0, stream>>>(W2, w2q, sw);
  ccattn_main_k<<<256, 512, 0, stream>>>(x, W1, b1, w2q, sw, b2, out);
}